// Round 1
// baseline (335.000 us; speedup 1.0000x reference)
//
#include <hip/hip_runtime.h>

#define NN 100000
#define NE 1600000
#define NB 782            // buckets of 128 dst nodes
#define NBPAD 1024        // padded bucket count for scan (4 per thread)
#define CAPB 3072         // staging/grouped capacity per bucket (mean 2046, 22 sigma)
#define EPB 8192          // edges per binning block
#define NROWPAD 100096    // 782 * 128, dgemm row padding
#define DPAD 136          // T-tile row stride (ushort)
#define OPAD 72           // O-tile row stride (ushort)

typedef __attribute__((ext_vector_type(8))) short short8;
typedef __attribute__((ext_vector_type(4))) float f32x4;

// ---------------- helpers ----------------
__device__ __forceinline__ unsigned short bf16rn(float f) {
    unsigned u = __float_as_uint(f);
    return (unsigned short)((u + 0x7FFFu + ((u >> 16) & 1u)) >> 16);
}
__device__ __forceinline__ uint2 packbf4(float4 v) {
    uint2 u;
    u.x = (unsigned)bf16rn(v.x) | ((unsigned)bf16rn(v.y) << 16);
    u.y = (unsigned)bf16rn(v.z) | ((unsigned)bf16rn(v.w) << 16);
    return u;
}
__device__ __forceinline__ unsigned packbf2(float x, float y) {
    return (unsigned)bf16rn(x) | ((unsigned)bf16rn(y) << 16);
}
// accumulate 8 bf16 features (one uint4) scaled by q into a[0..7]
__device__ __forceinline__ void bf8acc(float* a, uint4 v, float q) {
    a[0] = fmaf(__uint_as_float(v.x << 16), q, a[0]);
    a[1] = fmaf(__uint_as_float(v.x & 0xFFFF0000u), q, a[1]);
    a[2] = fmaf(__uint_as_float(v.y << 16), q, a[2]);
    a[3] = fmaf(__uint_as_float(v.y & 0xFFFF0000u), q, a[3]);
    a[4] = fmaf(__uint_as_float(v.z << 16), q, a[4]);
    a[5] = fmaf(__uint_as_float(v.z & 0xFFFF0000u), q, a[5]);
    a[6] = fmaf(__uint_as_float(v.w << 16), q, a[6]);
    a[7] = fmaf(__uint_as_float(v.w & 0xFFFF0000u), q, a[7]);
}
// non-temporal 8B edge-stream load -> (src, qnorm_bits)
__device__ __forceinline__ uint2 ldnt2(const unsigned long long* p) {
    unsigned long long v = __builtin_nontemporal_load(p);
    uint2 r;
    r.x = (unsigned)v;
    r.y = (unsigned)(v >> 32);
    return r;
}

// ---------------- dtype detector ----------------
__global__ void detect_i64_k(const unsigned* __restrict__ ei, int* __restrict__ flag) {
    unsigned w = ei[2 * threadIdx.x + 1];
    unsigned long long b = __ballot(w == 0u);
    if (threadIdx.x == 0) *flag = (b == 0xFFFFFFFFFFFFFFFFull) ? 1 : 0;
}
__device__ __forceinline__ int load_node(const void* ei, int i64, long long idx) {
    return i64 ? (int)((const long long*)ei)[idx] : ((const int*)ei)[idx];
}

// ---------------- fp32 -> bf16 cast (streaming) ----------------
__global__ void cast_bf16_k(const float* __restrict__ in, ushort* __restrict__ outb,
                            long long n4) {
    long long i = (long long)blockIdx.x * 256 + threadIdx.x;
    if (i >= n4) return;
    ((uint2*)outb)[i] = packbf4(((const float4*)in)[i]);
}

// ---------------- weights -> bf16 col-major ----------------
__global__ void prep_wt_k(const float* __restrict__ W1, const float* __restrict__ W2,
                          ushort* __restrict__ W1t, ushort* __restrict__ W2t) {
    int i = blockIdx.x * 256 + threadIdx.x;
    if (i < 128 * 128) {
        int k = i >> 7, n = i & 127;
        W1t[n * 128 + k] = bf16rn(W1[k * 128 + n]);
    }
    if (i < 128 * 64) {
        int k = i >> 6, n = i & 63;
        W2t[n * 128 + k] = bf16rn(W2[k * 64 + n]);
    }
}

// ---------------- LDS-staged binning: edges -> per-bucket staging ----------------
__global__ __launch_bounds__(256) void binfill_k(const void* __restrict__ ei,
                                                 const int* __restrict__ flag,
                                                 int* __restrict__ cur,
                                                 unsigned* __restrict__ bstage) {
    __shared__ unsigned binned[EPB];      // 32 KB
    __shared__ int lcnt[NBPAD];
    __shared__ int lpos[NBPAD];
    __shared__ int gbase[NBPAD];
    __shared__ int tsum[256];
    int tid = threadIdx.x;
    long long e0 = (long long)blockIdx.x * EPB;
    int i64 = *flag;

    for (int i = tid; i < NBPAD; i += 256) lcnt[i] = 0;
    __syncthreads();

    // pass 1: histogram destination buckets
    for (int i = tid; i < EPB; i += 256) {
        long long e = e0 + i;
        if (e < NE) {
            int d = load_node(ei, i64, (long long)NE + e);
            atomicAdd(&lcnt[d >> 7], 1);
        }
    }
    __syncthreads();

    // exclusive scan over NBPAD counters, 4 consecutive per thread
    int base = tid * 4;
    int c0 = lcnt[base], c1 = lcnt[base + 1], c2 = lcnt[base + 2], c3 = lcnt[base + 3];
    int s = c0 + c1 + c2 + c3;
    tsum[tid] = s;
    __syncthreads();
    for (int off = 1; off < 256; off <<= 1) {
        int v = (tid >= off) ? tsum[tid - off] : 0;
        __syncthreads();
        tsum[tid] += v;
        __syncthreads();
    }
    int excl = tsum[tid] - s;
    int p0 = excl, p1 = excl + c0, p2 = p1 + c1, p3 = p2 + c2;
    lcnt[base] = p0; lcnt[base + 1] = p1; lcnt[base + 2] = p2; lcnt[base + 3] = p3;
    lpos[base] = p0; lpos[base + 1] = p1; lpos[base + 2] = p2; lpos[base + 3] = p3;
    if (base < NB)     gbase[base]     = c0 ? atomicAdd(&cur[base], c0) : 0;
    if (base + 1 < NB) gbase[base + 1] = c1 ? atomicAdd(&cur[base + 1], c1) : 0;
    if (base + 2 < NB) gbase[base + 2] = c2 ? atomicAdd(&cur[base + 2], c2) : 0;
    if (base + 3 < NB) gbase[base + 3] = c3 ? atomicAdd(&cur[base + 3], c3) : 0;
    __syncthreads();

    // pass 2: re-read (L2-hot) and scatter into binned LDS
    for (int i = tid; i < EPB; i += 256) {
        long long e = e0 + i;
        if (e < NE) {
            int sv = load_node(ei, i64, e);
            int d  = load_node(ei, i64, (long long)NE + e);
            int b  = d >> 7;
            int p  = atomicAdd(&lpos[b], 1);
            binned[p] = ((unsigned)(d & 127) << 17) | (unsigned)sv;
        }
    }
    __syncthreads();

    // flush contiguous runs into bucket regions
    for (int b = tid; b < NB; b += 256) {
        int start = lcnt[b], endp = lpos[b];
        int gb = gbase[b];
        unsigned* dst = bstage + (long long)b * CAPB;
        for (int k = start; k < endp; k++) {
            int go = gb + (k - start);
            if (go < CAPB) dst[go] = binned[k];
        }
    }
}

// ---------------- per-bucket LDS regroup -> dense CSR (uint2 {src,dst}) + deg ----------------
__global__ __launch_bounds__(256) void regroup_k(const int* __restrict__ cur,
                                                 const unsigned* __restrict__ bstage,
                                                 int* __restrict__ cnt,
                                                 int* __restrict__ rowstart,
                                                 uint2* __restrict__ g2,
                                                 float* __restrict__ dinv) {
    __shared__ unsigned stash[CAPB];
    __shared__ int lcnt[128], lofs[128], lpos[128], sc[128];
    int tid = threadIdx.x;
    int b = blockIdx.x;

    int total = cur[b];
    if (total > CAPB) total = CAPB;
    const unsigned* seg = bstage + (long long)b * CAPB;
    for (int i = tid; i < total; i += 256) stash[i] = seg[i];
    __syncthreads();

    if (tid < 128) { lcnt[tid] = 0; lpos[tid] = 0; }
    __syncthreads();
    for (int i = tid; i < total; i += 256)
        atomicAdd(&lcnt[stash[i] >> 17], 1);
    __syncthreads();

    if (tid < 128) sc[tid] = lcnt[tid];
    __syncthreads();
    for (int off = 1; off < 128; off <<= 1) {
        int v = 0;
        if (tid < 128 && tid >= off) v = sc[tid - off];
        __syncthreads();
        if (tid < 128) sc[tid] += v;
        __syncthreads();
    }
    if (tid < 128) {
        lofs[tid] = sc[tid] - lcnt[tid];
        int node = b * 128 + tid;
        if (node < NN) {
            cnt[node] = lcnt[tid];
            rowstart[node] = b * CAPB + lofs[tid];
            dinv[node] = rsqrtf((float)(lcnt[tid] + 1));   // +1: self-loop
        }
    }
    __syncthreads();

    uint2* g = g2 + (long long)b * CAPB;
    for (int i = tid; i < total; i += 256) {
        unsigned e = stash[i];
        int nl = e >> 17;
        int p = atomicAdd(&lpos[nl], 1);
        g[lofs[nl] + p] = make_uint2(e & 0x1FFFFu, (unsigned)(b * 128 + nl));
    }
}

// ---------------- per-edge norm precompute: {src,dst} -> {src, dinv[src]*dinv[dst]} ----------------
__global__ __launch_bounds__(256) void qn_k(const int* __restrict__ cur,
                                            const float* __restrict__ dinv,
                                            uint2* __restrict__ g2) {
    int b = blockIdx.x;
    int total = cur[b];
    if (total > CAPB) total = CAPB;
    uint2* g = g2 + (long long)b * CAPB;
    for (int i = threadIdx.x; i < total; i += 256) {
        uint2 e = g[i];
        float q = dinv[e.x] * dinv[e.y];
        g[i] = make_uint2(e.x, __float_as_uint(q));
    }
}

// ---------------- 4-edge gather+fma, 16 B/lane ----------------
template <int LPN>
__device__ __forceinline__ void gf4(const uint4* __restrict__ h4, int lane,
                                    uint2 e0, uint2 e1, uint2 e2, uint2 e3,
                                    float* a, float* b) {
    uint4 v0 = h4[e0.x * LPN + lane];
    uint4 v1 = h4[e1.x * LPN + lane];
    uint4 v2 = h4[e2.x * LPN + lane];
    uint4 v3 = h4[e3.x * LPN + lane];
    bf8acc(a, v0, __uint_as_float(e0.y));
    bf8acc(b, v1, __uint_as_float(e1.y));
    bf8acc(a, v2, __uint_as_float(e2.y));
    bf8acc(b, v3, __uint_as_float(e3.y));
}

// ---------------- CSR pull v2: 16 B/lane gathers, precomputed norms, pipelined stream ----------------
template <int LPN, bool BIAS, bool OUTB>
__global__ __launch_bounds__(256) void pull2_k(const uint2* __restrict__ g2,
                                               const int* __restrict__ rowstart,
                                               const int* __restrict__ cnt,
                                               const float* __restrict__ dinv,
                                               const ushort* __restrict__ hb,
                                               const float* __restrict__ bias,
                                               void* __restrict__ out) {
    int tid = threadIdx.x;
    int node = blockIdx.x * (256 / LPN) + tid / LPN;
    int lane = tid & (LPN - 1);
    if (node >= NN) return;

    const uint4* h4 = (const uint4*)hb;
    float di = dinv[node];
    float w0 = di * di;
    float a[8] = {0.f, 0.f, 0.f, 0.f, 0.f, 0.f, 0.f, 0.f};
    float b[8] = {0.f, 0.f, 0.f, 0.f, 0.f, 0.f, 0.f, 0.f};
    bf8acc(a, h4[(unsigned)node * LPN + lane], w0);   // self-loop term

    int deg = cnt[node];
    const unsigned long long* rowq =
        (const unsigned long long*)(g2 + rowstart[node]);

    int j = 0;
    if (deg >= 8) {
        uint2 e0 = ldnt2(rowq + 0), e1 = ldnt2(rowq + 1);
        uint2 e2 = ldnt2(rowq + 2), e3 = ldnt2(rowq + 3);
        for (; j + 7 < deg; j += 4) {
            uint2 f0 = ldnt2(rowq + j + 4), f1 = ldnt2(rowq + j + 5);
            uint2 f2 = ldnt2(rowq + j + 6), f3 = ldnt2(rowq + j + 7);
            gf4<LPN>(h4, lane, e0, e1, e2, e3, a, b);
            e0 = f0; e1 = f1; e2 = f2; e3 = f3;
        }
        gf4<LPN>(h4, lane, e0, e1, e2, e3, a, b);
        j += 4;
    } else if (deg >= 4) {
        gf4<LPN>(h4, lane, ldnt2(rowq + 0), ldnt2(rowq + 1),
                 ldnt2(rowq + 2), ldnt2(rowq + 3), a, b);
        j = 4;
    }
    for (; j < deg; j++) {
        uint2 e = ldnt2(rowq + j);
        bf8acc(a, h4[e.x * LPN + lane], __uint_as_float(e.y));
    }

    float o[8];
#pragma unroll
    for (int k = 0; k < 8; k++) o[k] = a[k] + b[k];
    if (BIAS) {
        float4 b0 = ((const float4*)bias)[2 * lane];
        float4 b1 = ((const float4*)bias)[2 * lane + 1];
        o[0] += b0.x; o[1] += b0.y; o[2] += b0.z; o[3] += b0.w;
        o[4] += b1.x; o[5] += b1.y; o[6] += b1.z; o[7] += b1.w;
    }
    if (OUTB) {
        uint4 p;
        p.x = packbf2(o[0], o[1]);
        p.y = packbf2(o[2], o[3]);
        p.z = packbf2(o[4], o[5]);
        p.w = packbf2(o[6], o[7]);
        ((uint4*)out)[(unsigned)node * LPN + lane] = p;
    } else {
        float4 lo = make_float4(o[0], o[1], o[2], o[3]);
        float4 hi = make_float4(o[4], o[5], o[6], o[7]);
        ((float4*)out)[(unsigned)node * (2 * LPN) + 2 * lane] = lo;
        ((float4*)out)[(unsigned)node * (2 * LPN) + 2 * lane + 1] = hi;
    }
}

// ---------------- MFMA fused double GEMM ----------------
__global__ __launch_bounds__(256) void dgemm_mfma_k(const ushort* __restrict__ Ab,
                                                    const ushort* __restrict__ W1t,
                                                    const float* __restrict__ b1,
                                                    const ushort* __restrict__ W2t,
                                                    ushort* __restrict__ H2b) {
    __shared__ ushort Tt[4][32 * DPAD];
    __shared__ ushort Ot[4][32 * OPAD];
    int tid = threadIdx.x;
    int wv = tid >> 6, lane = tid & 63;
    int m16 = lane & 15, quad = lane >> 4;
    int row0 = blockIdx.x * 128 + wv * 32;

    short8 af[2][4];
#pragma unroll
    for (int mt = 0; mt < 2; mt++)
#pragma unroll
        for (int kc = 0; kc < 4; kc++)
            af[mt][kc] = *(const short8*)(Ab + (long long)(row0 + mt * 16 + m16) * 128
                                          + kc * 32 + quad * 8);
    f32x4 accA[2][8];
#pragma unroll
    for (int mt = 0; mt < 2; mt++)
#pragma unroll
        for (int nt = 0; nt < 8; nt++) accA[mt][nt] = (f32x4){0.f, 0.f, 0.f, 0.f};

#pragma unroll
    for (int nt = 0; nt < 8; nt++) {
#pragma unroll
        for (int kc = 0; kc < 4; kc++) {
            short8 bf = *(const short8*)(W1t + (nt * 16 + m16) * 128 + kc * 32 + quad * 8);
            accA[0][nt] = __builtin_amdgcn_mfma_f32_16x16x32_bf16(af[0][kc], bf, accA[0][nt], 0, 0, 0);
            accA[1][nt] = __builtin_amdgcn_mfma_f32_16x16x32_bf16(af[1][kc], bf, accA[1][nt], 0, 0, 0);
        }
    }

#pragma unroll
    for (int nt = 0; nt < 8; nt++) {
        float bb = b1[nt * 16 + m16];
#pragma unroll
        for (int mt = 0; mt < 2; mt++)
#pragma unroll
            for (int r = 0; r < 4; r++) {
                float v = fmaxf(accA[mt][nt][r] + bb, 0.f);
                Tt[wv][(mt * 16 + quad * 4 + r) * DPAD + nt * 16 + m16] = bf16rn(v);
            }
    }
    __syncthreads();

    f32x4 accB[2][4];
#pragma unroll
    for (int mt = 0; mt < 2; mt++)
#pragma unroll
        for (int nt = 0; nt < 4; nt++) accB[mt][nt] = (f32x4){0.f, 0.f, 0.f, 0.f};

#pragma unroll
    for (int nt = 0; nt < 4; nt++) {
#pragma unroll
        for (int kc = 0; kc < 4; kc++) {
            short8 bf = *(const short8*)(W2t + (nt * 16 + m16) * 128 + kc * 32 + quad * 8);
#pragma unroll
            for (int mt = 0; mt < 2; mt++) {
                short8 aT = *(const short8*)(&Tt[wv][(mt * 16 + m16) * DPAD + kc * 32 + quad * 8]);
                accB[mt][nt] = __builtin_amdgcn_mfma_f32_16x16x32_bf16(aT, bf, accB[mt][nt], 0, 0, 0);
            }
        }
    }

#pragma unroll
    for (int nt = 0; nt < 4; nt++)
#pragma unroll
        for (int mt = 0; mt < 2; mt++)
#pragma unroll
            for (int r = 0; r < 4; r++)
                Ot[wv][(mt * 16 + quad * 4 + r) * OPAD + nt * 16 + m16] = bf16rn(accB[mt][nt][r]);
    __syncthreads();

    uint4* H4 = (uint4*)H2b;
#pragma unroll
    for (int it = 0; it < 4; it++) {
        int idx = it * 64 + lane;
        int r = idx >> 3, c = idx & 7;
        int grow = row0 + r;
        if (grow < NN) {
            uint4 v = *(const uint4*)(&Ot[wv][r * OPAD + c * 8]);
            H4[(long long)grow * 8 + c] = v;
        }
    }
}

// ---------------- launch ----------------
extern "C" void kernel_launch(void* const* d_in, const int* in_sizes, int n_in,
                              void* d_out, int out_size, void* d_ws, size_t ws_size,
                              hipStream_t stream) {
    const float* x  = (const float*)d_in[0];
    const void*  ei = d_in[1];
    const float* W1 = (const float*)d_in[2];
    const float* b1 = (const float*)d_in[3];
    const float* W2 = (const float*)d_in[4];
    const float* b2 = (const float*)d_in[5];
    float* out = (float*)d_out;
    char* ws = (char*)d_ws;

    // Layout (~98 MB of the >=125 MB proven ws):
    int*      flag     = (int*)ws;
    int*      cur      = (int*)(ws + 0x1000);        // 3.1 KB
    int*      cnt      = (int*)(ws + 0x10000);       // 400 KB
    int*      rowstart = (int*)(ws + 0x80000);       // 400 KB
    unsigned* bstage   = (unsigned*)(ws + 0x100000); // 782*3072*4 = 9.6 MB
    uint2*    g2       = (uint2*)(ws + 0xB00000);    // 782*3072*8 = 19.2 MB
    ushort*   xb       = (ushort*)(ws + 0x1E00000);  // 25.6 MB
    ushort*   aggxb    = (ushort*)(ws + 0x3700000);  // 25.6 MB (+pad rows)
    ushort*   h2b      = (ushort*)(ws + 0x5000000);  // 12.8 MB
    ushort*   W1t      = (ushort*)(ws + 0x5D00000);  // 32 KB
    ushort*   W2t      = (ushort*)(ws + 0x5D10000);  // 16 KB
    float*    dinv     = (float*)(ws + 0x5D20000);   // 400 KB

    hipMemsetAsync(cur, 0, NB * sizeof(int), stream);
    detect_i64_k<<<1, 64, 0, stream>>>((const unsigned*)ei, flag);
    cast_bf16_k<<<(NN * 32 + 255) / 256, 256, 0, stream>>>(x, xb, (long long)NN * 32);
    prep_wt_k<<<64, 256, 0, stream>>>(W1, W2, W1t, W2t);
    binfill_k<<<(NE + EPB - 1) / EPB, 256, 0, stream>>>(ei, flag, cur, bstage);
    regroup_k<<<NB, 256, 0, stream>>>(cur, bstage, cnt, rowstart, g2, dinv);
    qn_k<<<NB, 256, 0, stream>>>(cur, dinv, g2);

    // layer 1 aggregate-first: aggxb = bf16( A_norm @ x ), 16 nodes/block (LPN=16)
    pull2_k<16, false, true><<<(NN + 15) / 16, 256, 0, stream>>>(g2, rowstart, cnt, dinv,
                                                                 xb, nullptr, aggxb);
    // fused transforms on MFMA: h2b = bf16( relu(aggxb@W1 + b1) @ W2 )
    dgemm_mfma_k<<<NROWPAD / 128, 256, 0, stream>>>(aggxb, W1t, b1, W2t, h2b);

    // layer 2 aggregate: out = A_norm @ h2 + b2 (fp32 out), 32 nodes/block (LPN=8)
    pull2_k<8, true, false><<<(NN + 31) / 32, 256, 0, stream>>>(g2, rowstart, cnt, dinv,
                                                                h2b, b2, out);
}

// Round 2
// 325.652 us; speedup vs baseline: 1.0287x; 1.0287x over previous
//
#include <hip/hip_runtime.h>

#define NN 100000
#define NE 1600000
#define NB 782            // buckets of 128 dst nodes
#define NBPAD 1024        // padded bucket count for scan (4 per thread)
#define CAPB 3072         // staging/grouped capacity per bucket (mean 2046, 22 sigma)
#define EPB 8192          // edges per binning block
#define NROWPAD 100096    // 782 * 128, dgemm row padding
#define DPAD 136          // T-tile row stride (ushort)
#define OPAD 72           // O-tile row stride (ushort)

typedef __attribute__((ext_vector_type(8))) short short8;
typedef __attribute__((ext_vector_type(4))) float f32x4;

// ---------------- helpers ----------------
__device__ __forceinline__ unsigned short bf16rn(float f) {
    unsigned u = __float_as_uint(f);
    return (unsigned short)((u + 0x7FFFu + ((u >> 16) & 1u)) >> 16);
}
__device__ __forceinline__ float4 bf2x4(uint2 g) {
    float4 r;
    r.x = __uint_as_float(g.x << 16);
    r.y = __uint_as_float(g.x & 0xFFFF0000u);
    r.z = __uint_as_float(g.y << 16);
    r.w = __uint_as_float(g.y & 0xFFFF0000u);
    return r;
}
__device__ __forceinline__ uint2 packbf4(float4 v) {
    uint2 u;
    u.x = (unsigned)bf16rn(v.x) | ((unsigned)bf16rn(v.y) << 16);
    u.y = (unsigned)bf16rn(v.z) | ((unsigned)bf16rn(v.w) << 16);
    return u;
}
// accumulate 4 bf16 features (one uint2) scaled by fp32 norm bits
__device__ __forceinline__ void acc4(float4& a, uint2 v, unsigned qb) {
    float q = __uint_as_float(qb);
    a.x = fmaf(__uint_as_float(v.x << 16), q, a.x);
    a.y = fmaf(__uint_as_float(v.x & 0xFFFF0000u), q, a.y);
    a.z = fmaf(__uint_as_float(v.y << 16), q, a.z);
    a.w = fmaf(__uint_as_float(v.y & 0xFFFF0000u), q, a.w);
}

// ---------------- dtype detector ----------------
__global__ void detect_i64_k(const unsigned* __restrict__ ei, int* __restrict__ flag) {
    unsigned w = ei[2 * threadIdx.x + 1];
    unsigned long long b = __ballot(w == 0u);
    if (threadIdx.x == 0) *flag = (b == 0xFFFFFFFFFFFFFFFFull) ? 1 : 0;
}
__device__ __forceinline__ int load_node(const void* ei, int i64, long long idx) {
    return i64 ? (int)((const long long*)ei)[idx] : ((const int*)ei)[idx];
}

// ---------------- fp32 -> bf16 cast (streaming) ----------------
__global__ void cast_bf16_k(const float* __restrict__ in, ushort* __restrict__ outb,
                            long long n4) {
    long long i = (long long)blockIdx.x * 256 + threadIdx.x;
    if (i >= n4) return;
    ((uint2*)outb)[i] = packbf4(((const float4*)in)[i]);
}

// ---------------- weights -> bf16 col-major ----------------
__global__ void prep_wt_k(const float* __restrict__ W1, const float* __restrict__ W2,
                          ushort* __restrict__ W1t, ushort* __restrict__ W2t) {
    int i = blockIdx.x * 256 + threadIdx.x;
    if (i < 128 * 128) {
        int k = i >> 7, n = i & 127;
        W1t[n * 128 + k] = bf16rn(W1[k * 128 + n]);
    }
    if (i < 128 * 64) {
        int k = i >> 6, n = i & 63;
        W2t[n * 128 + k] = bf16rn(W2[k * 64 + n]);
    }
}

// ---------------- LDS-staged binning: edges -> per-bucket staging ----------------
__global__ __launch_bounds__(256) void binfill_k(const void* __restrict__ ei,
                                                 const int* __restrict__ flag,
                                                 int* __restrict__ cur,
                                                 unsigned* __restrict__ bstage) {
    __shared__ unsigned binned[EPB];      // 32 KB
    __shared__ int lcnt[NBPAD];
    __shared__ int lpos[NBPAD];
    __shared__ int gbase[NBPAD];
    __shared__ int tsum[256];
    int tid = threadIdx.x;
    long long e0 = (long long)blockIdx.x * EPB;
    int i64 = *flag;

    for (int i = tid; i < NBPAD; i += 256) lcnt[i] = 0;
    __syncthreads();

    // pass 1: histogram destination buckets
    for (int i = tid; i < EPB; i += 256) {
        long long e = e0 + i;
        if (e < NE) {
            int d = load_node(ei, i64, (long long)NE + e);
            atomicAdd(&lcnt[d >> 7], 1);
        }
    }
    __syncthreads();

    // exclusive scan over NBPAD counters, 4 consecutive per thread
    int base = tid * 4;
    int c0 = lcnt[base], c1 = lcnt[base + 1], c2 = lcnt[base + 2], c3 = lcnt[base + 3];
    int s = c0 + c1 + c2 + c3;
    tsum[tid] = s;
    __syncthreads();
    for (int off = 1; off < 256; off <<= 1) {
        int v = (tid >= off) ? tsum[tid - off] : 0;
        __syncthreads();
        tsum[tid] += v;
        __syncthreads();
    }
    int excl = tsum[tid] - s;
    int p0 = excl, p1 = excl + c0, p2 = p1 + c1, p3 = p2 + c2;
    lcnt[base] = p0; lcnt[base + 1] = p1; lcnt[base + 2] = p2; lcnt[base + 3] = p3;
    lpos[base] = p0; lpos[base + 1] = p1; lpos[base + 2] = p2; lpos[base + 3] = p3;
    if (base < NB)     gbase[base]     = c0 ? atomicAdd(&cur[base], c0) : 0;
    if (base + 1 < NB) gbase[base + 1] = c1 ? atomicAdd(&cur[base + 1], c1) : 0;
    if (base + 2 < NB) gbase[base + 2] = c2 ? atomicAdd(&cur[base + 2], c2) : 0;
    if (base + 3 < NB) gbase[base + 3] = c3 ? atomicAdd(&cur[base + 3], c3) : 0;
    __syncthreads();

    // pass 2: re-read (L2-hot) and scatter into binned LDS
    for (int i = tid; i < EPB; i += 256) {
        long long e = e0 + i;
        if (e < NE) {
            int sv = load_node(ei, i64, e);
            int d  = load_node(ei, i64, (long long)NE + e);
            int b  = d >> 7;
            int p  = atomicAdd(&lpos[b], 1);
            binned[p] = ((unsigned)(d & 127) << 17) | (unsigned)sv;
        }
    }
    __syncthreads();

    // flush contiguous runs into bucket regions
    for (int b = tid; b < NB; b += 256) {
        int start = lcnt[b], endp = lpos[b];
        int gb = gbase[b];
        unsigned* dst = bstage + (long long)b * CAPB;
        for (int k = start; k < endp; k++) {
            int go = gb + (k - start);
            if (go < CAPB) dst[go] = binned[k];
        }
    }
}

// ---------------- per-bucket LDS regroup -> dense CSR (uint2 {src,dst}) + deg ----------------
__global__ __launch_bounds__(256) void regroup_k(const int* __restrict__ cur,
                                                 const unsigned* __restrict__ bstage,
                                                 int* __restrict__ cnt,
                                                 int* __restrict__ rowstart,
                                                 uint2* __restrict__ g2,
                                                 float* __restrict__ dinv) {
    __shared__ unsigned stash[CAPB];
    __shared__ int lcnt[128], lofs[128], lpos[128], sc[128];
    int tid = threadIdx.x;
    int b = blockIdx.x;

    int total = cur[b];
    if (total > CAPB) total = CAPB;
    const unsigned* seg = bstage + (long long)b * CAPB;
    for (int i = tid; i < total; i += 256) stash[i] = seg[i];
    __syncthreads();

    if (tid < 128) { lcnt[tid] = 0; lpos[tid] = 0; }
    __syncthreads();
    for (int i = tid; i < total; i += 256)
        atomicAdd(&lcnt[stash[i] >> 17], 1);
    __syncthreads();

    if (tid < 128) sc[tid] = lcnt[tid];
    __syncthreads();
    for (int off = 1; off < 128; off <<= 1) {
        int v = 0;
        if (tid < 128 && tid >= off) v = sc[tid - off];
        __syncthreads();
        if (tid < 128) sc[tid] += v;
        __syncthreads();
    }
    if (tid < 128) {
        lofs[tid] = sc[tid] - lcnt[tid];
        int node = b * 128 + tid;
        if (node < NN) {
            cnt[node] = lcnt[tid];
            rowstart[node] = b * CAPB + lofs[tid];
            dinv[node] = rsqrtf((float)(lcnt[tid] + 1));   // +1: self-loop
        }
    }
    __syncthreads();

    uint2* g = g2 + (long long)b * CAPB;
    for (int i = tid; i < total; i += 256) {
        unsigned e = stash[i];
        int nl = e >> 17;
        int p = atomicAdd(&lpos[nl], 1);
        g[lofs[nl] + p] = make_uint2(e & 0x1FFFFu, (unsigned)(b * 128 + nl));
    }
}

// ---------------- per-edge norm precompute: {src,dst} -> {src, dinv[src]*dinv[dst]} ----------------
__global__ __launch_bounds__(256) void qn_k(const int* __restrict__ cur,
                                            const float* __restrict__ dinv,
                                            uint2* __restrict__ g2) {
    int b = blockIdx.x;
    int total = cur[b];
    if (total > CAPB) total = CAPB;
    uint2* g = g2 + (long long)b * CAPB;
    for (int i = threadIdx.x; i < total; i += 256) {
        uint2 e = g[i];
        float q = dinv[e.x] * dinv[e.y];
        g[i] = make_uint2(e.x, __float_as_uint(q));
    }
}

// ---------------- CSR pull v3: uint2 gathers + double-buffered gather pipeline ----------------
// Per quad of edges: stream entries prefetched 1 quad ahead; GATHERS issued 1 quad ahead
// (consumed a full loop iteration after issue -> per-wave latency cover, x8 waves/SIMD).
template <int LPN, bool BIAS, bool OUTB>
__global__ __launch_bounds__(256) void pull3_k(const uint2* __restrict__ g2,
                                               const int* __restrict__ rowstart,
                                               const int* __restrict__ cnt,
                                               const float* __restrict__ dinv,
                                               const ushort* __restrict__ hb,
                                               const float* __restrict__ bias,
                                               void* __restrict__ out) {
    int tid = threadIdx.x;
    int node = blockIdx.x * (256 / LPN) + tid / LPN;
    int lane = tid & (LPN - 1);
    if (node >= NN) return;

    const uint2* h2 = (const uint2*)hb;
    float di = dinv[node];
    float w0 = di * di;
    float4 A = make_float4(0.f, 0.f, 0.f, 0.f);
    float4 B = make_float4(0.f, 0.f, 0.f, 0.f);
    {
        float4 hv = bf2x4(h2[(unsigned)node * LPN + lane]);
        A.x = hv.x * w0; A.y = hv.y * w0; A.z = hv.z * w0; A.w = hv.w * w0;
    }

    int deg = cnt[node];
    const uint2* row = g2 + rowstart[node];

    int j = 0;
    if (deg >= 4) {
        // prologue: stream quad 0 + issue its gathers
        uint2 e0 = row[0], e1 = row[1], e2 = row[2], e3 = row[3];
        uint2 v0 = h2[e0.x * LPN + lane];
        uint2 v1 = h2[e1.x * LPN + lane];
        uint2 v2 = h2[e2.x * LPN + lane];
        uint2 v3 = h2[e3.x * LPN + lane];
        for (; j + 8 <= deg; j += 4) {
            // stream for next quad (issue early)
            uint2 f0 = row[j + 4], f1 = row[j + 5], f2 = row[j + 6], f3 = row[j + 7];
            // consume current gathers (selective vmcnt: v* older than f*)
            acc4(A, v0, e0.y); acc4(B, v1, e1.y);
            acc4(A, v2, e2.y); acc4(B, v3, e3.y);
            // issue next gathers (consumed next iteration)
            uint2 w0v = h2[f0.x * LPN + lane];
            uint2 w1v = h2[f1.x * LPN + lane];
            uint2 w2v = h2[f2.x * LPN + lane];
            uint2 w3v = h2[f3.x * LPN + lane];
            e0 = f0; e1 = f1; e2 = f2; e3 = f3;
            v0 = w0v; v1 = w1v; v2 = w2v; v3 = w3v;
        }
        // epilogue: consume last full quad
        acc4(A, v0, e0.y); acc4(B, v1, e1.y);
        acc4(A, v2, e2.y); acc4(B, v3, e3.y);
        j += 4;
    }
    for (; j < deg; j++) {
        uint2 e = row[j];
        uint2 v = h2[e.x * LPN + lane];
        acc4(A, v, e.y);
    }

    float4 o;
    o.x = A.x + B.x; o.y = A.y + B.y; o.z = A.z + B.z; o.w = A.w + B.w;
    if (BIAS) {
        float4 bb = ((const float4*)bias)[lane];
        o.x += bb.x; o.y += bb.y; o.z += bb.z; o.w += bb.w;
    }
    if (OUTB)
        ((uint2*)out)[(unsigned)node * LPN + lane] = packbf4(o);
    else
        ((float4*)out)[(unsigned)node * LPN + lane] = o;
}

// ---------------- MFMA fused double GEMM ----------------
__global__ __launch_bounds__(256) void dgemm_mfma_k(const ushort* __restrict__ Ab,
                                                    const ushort* __restrict__ W1t,
                                                    const float* __restrict__ b1,
                                                    const ushort* __restrict__ W2t,
                                                    ushort* __restrict__ H2b) {
    __shared__ ushort Tt[4][32 * DPAD];
    __shared__ ushort Ot[4][32 * OPAD];
    int tid = threadIdx.x;
    int wv = tid >> 6, lane = tid & 63;
    int m16 = lane & 15, quad = lane >> 4;
    int row0 = blockIdx.x * 128 + wv * 32;

    short8 af[2][4];
#pragma unroll
    for (int mt = 0; mt < 2; mt++)
#pragma unroll
        for (int kc = 0; kc < 4; kc++)
            af[mt][kc] = *(const short8*)(Ab + (long long)(row0 + mt * 16 + m16) * 128
                                          + kc * 32 + quad * 8);
    f32x4 accA[2][8];
#pragma unroll
    for (int mt = 0; mt < 2; mt++)
#pragma unroll
        for (int nt = 0; nt < 8; nt++) accA[mt][nt] = (f32x4){0.f, 0.f, 0.f, 0.f};

#pragma unroll
    for (int nt = 0; nt < 8; nt++) {
#pragma unroll
        for (int kc = 0; kc < 4; kc++) {
            short8 bf = *(const short8*)(W1t + (nt * 16 + m16) * 128 + kc * 32 + quad * 8);
            accA[0][nt] = __builtin_amdgcn_mfma_f32_16x16x32_bf16(af[0][kc], bf, accA[0][nt], 0, 0, 0);
            accA[1][nt] = __builtin_amdgcn_mfma_f32_16x16x32_bf16(af[1][kc], bf, accA[1][nt], 0, 0, 0);
        }
    }

#pragma unroll
    for (int nt = 0; nt < 8; nt++) {
        float bb = b1[nt * 16 + m16];
#pragma unroll
        for (int mt = 0; mt < 2; mt++)
#pragma unroll
            for (int r = 0; r < 4; r++) {
                float v = fmaxf(accA[mt][nt][r] + bb, 0.f);
                Tt[wv][(mt * 16 + quad * 4 + r) * DPAD + nt * 16 + m16] = bf16rn(v);
            }
    }
    __syncthreads();

    f32x4 accB[2][4];
#pragma unroll
    for (int mt = 0; mt < 2; mt++)
#pragma unroll
        for (int nt = 0; nt < 4; nt++) accB[mt][nt] = (f32x4){0.f, 0.f, 0.f, 0.f};

#pragma unroll
    for (int nt = 0; nt < 4; nt++) {
#pragma unroll
        for (int kc = 0; kc < 4; kc++) {
            short8 bf = *(const short8*)(W2t + (nt * 16 + m16) * 128 + kc * 32 + quad * 8);
#pragma unroll
            for (int mt = 0; mt < 2; mt++) {
                short8 aT = *(const short8*)(&Tt[wv][(mt * 16 + m16) * DPAD + kc * 32 + quad * 8]);
                accB[mt][nt] = __builtin_amdgcn_mfma_f32_16x16x32_bf16(aT, bf, accB[mt][nt], 0, 0, 0);
            }
        }
    }

#pragma unroll
    for (int nt = 0; nt < 4; nt++)
#pragma unroll
        for (int mt = 0; mt < 2; mt++)
#pragma unroll
            for (int r = 0; r < 4; r++)
                Ot[wv][(mt * 16 + quad * 4 + r) * OPAD + nt * 16 + m16] = bf16rn(accB[mt][nt][r]);
    __syncthreads();

    uint4* H4 = (uint4*)H2b;
#pragma unroll
    for (int it = 0; it < 4; it++) {
        int idx = it * 64 + lane;
        int r = idx >> 3, c = idx & 7;
        int grow = row0 + r;
        if (grow < NN) {
            uint4 v = *(const uint4*)(&Ot[wv][r * OPAD + c * 8]);
            H4[(long long)grow * 8 + c] = v;
        }
    }
}

// ---------------- launch ----------------
extern "C" void kernel_launch(void* const* d_in, const int* in_sizes, int n_in,
                              void* d_out, int out_size, void* d_ws, size_t ws_size,
                              hipStream_t stream) {
    const float* x  = (const float*)d_in[0];
    const void*  ei = d_in[1];
    const float* W1 = (const float*)d_in[2];
    const float* b1 = (const float*)d_in[3];
    const float* W2 = (const float*)d_in[4];
    const float* b2 = (const float*)d_in[5];
    float* out = (float*)d_out;
    char* ws = (char*)d_ws;

    // Layout (~98 MB of the >=125 MB proven ws):
    int*      flag     = (int*)ws;
    int*      cur      = (int*)(ws + 0x1000);        // 3.1 KB
    int*      cnt      = (int*)(ws + 0x10000);       // 400 KB
    int*      rowstart = (int*)(ws + 0x80000);       // 400 KB
    unsigned* bstage   = (unsigned*)(ws + 0x100000); // 782*3072*4 = 9.6 MB
    uint2*    g2       = (uint2*)(ws + 0xB00000);    // 782*3072*8 = 19.2 MB
    ushort*   xb       = (ushort*)(ws + 0x1E00000);  // 25.6 MB
    ushort*   aggxb    = (ushort*)(ws + 0x3700000);  // 25.6 MB (+pad rows)
    ushort*   h2b      = (ushort*)(ws + 0x5000000);  // 12.8 MB
    ushort*   W1t      = (ushort*)(ws + 0x5D00000);  // 32 KB
    ushort*   W2t      = (ushort*)(ws + 0x5D10000);  // 16 KB
    float*    dinv     = (float*)(ws + 0x5D20000);   // 400 KB

    hipMemsetAsync(cur, 0, NB * sizeof(int), stream);
    detect_i64_k<<<1, 64, 0, stream>>>((const unsigned*)ei, flag);
    cast_bf16_k<<<(NN * 32 + 255) / 256, 256, 0, stream>>>(x, xb, (long long)NN * 32);
    prep_wt_k<<<64, 256, 0, stream>>>(W1, W2, W1t, W2t);
    binfill_k<<<(NE + EPB - 1) / EPB, 256, 0, stream>>>(ei, flag, cur, bstage);
    regroup_k<<<NB, 256, 0, stream>>>(cur, bstage, cnt, rowstart, g2, dinv);
    qn_k<<<NB, 256, 0, stream>>>(cur, dinv, g2);

    // layer 1 aggregate-first: aggxb = bf16( A_norm @ x ), LPN=32 (8 nodes/block)
    pull3_k<32, false, true><<<(NN + 7) / 8, 256, 0, stream>>>(g2, rowstart, cnt, dinv,
                                                               xb, nullptr, aggxb);
    // fused transforms on MFMA: h2b = bf16( relu(aggxb@W1 + b1) @ W2 )
    dgemm_mfma_k<<<NROWPAD / 128, 256, 0, stream>>>(aggxb, W1t, b1, W2t, h2b);

    // layer 2 aggregate: out = A_norm @ h2 + b2 (fp32 out), LPN=16 (16 nodes/block)
    pull3_k<16, true, false><<<(NN + 15) / 16, 256, 0, stream>>>(g2, rowstart, cnt, dinv,
                                                                 h2b, b2, out);
}

// Round 3
// 317.775 us; speedup vs baseline: 1.0542x; 1.0248x over previous
//
#include <hip/hip_runtime.h>

#define NN 100000
#define NE 1600000
#define NB 782            // buckets of 128 dst nodes
#define NBPAD 1024        // padded bucket count for scan (4 per thread)
#define CAPB 3072         // staging/grouped capacity per bucket (mean 2046, 22 sigma)
#define EPB 8192          // edges per binning block
#define NROWPAD 100096    // 782 * 128, dgemm row padding
#define DPAD 136          // T-tile row stride (ushort)
#define OPAD 72           // O-tile row stride (ushort)
#define MAXE 64           // LDS-staged edges per node (P(deg>64) ~ 0 at mean 16)

typedef __attribute__((ext_vector_type(8))) short short8;
typedef __attribute__((ext_vector_type(4))) float f32x4;

// ---------------- helpers ----------------
__device__ __forceinline__ unsigned short bf16rn(float f) {
    unsigned u = __float_as_uint(f);
    return (unsigned short)((u + 0x7FFFu + ((u >> 16) & 1u)) >> 16);
}
__device__ __forceinline__ float4 bf2x4(uint2 g) {
    float4 r;
    r.x = __uint_as_float(g.x << 16);
    r.y = __uint_as_float(g.x & 0xFFFF0000u);
    r.z = __uint_as_float(g.y << 16);
    r.w = __uint_as_float(g.y & 0xFFFF0000u);
    return r;
}
__device__ __forceinline__ uint2 packbf4(float4 v) {
    uint2 u;
    u.x = (unsigned)bf16rn(v.x) | ((unsigned)bf16rn(v.y) << 16);
    u.y = (unsigned)bf16rn(v.z) | ((unsigned)bf16rn(v.w) << 16);
    return u;
}
// accumulate 4 bf16 features (one uint2) scaled by fp32 norm bits
__device__ __forceinline__ void acc4(float4& a, uint2 v, unsigned qb) {
    float q = __uint_as_float(qb);
    a.x = fmaf(__uint_as_float(v.x << 16), q, a.x);
    a.y = fmaf(__uint_as_float(v.x & 0xFFFF0000u), q, a.y);
    a.z = fmaf(__uint_as_float(v.y << 16), q, a.z);
    a.w = fmaf(__uint_as_float(v.y & 0xFFFF0000u), q, a.w);
}
// bijective XCD-chunk swizzle (m204): dispatch-consecutive blocks stay on one XCD's chunk
__device__ __forceinline__ int xcd_swz(int bid, int nwg) {
    int q = nwg >> 3, r = nwg & 7;
    int x = bid & 7, j = bid >> 3;
    int base = (x < r) ? x * (q + 1) : r * (q + 1) + (x - r) * q;
    return base + j;
}

// ---------------- dtype detector ----------------
__global__ void detect_i64_k(const unsigned* __restrict__ ei, int* __restrict__ flag) {
    unsigned w = ei[2 * threadIdx.x + 1];
    unsigned long long b = __ballot(w == 0u);
    if (threadIdx.x == 0) *flag = (b == 0xFFFFFFFFFFFFFFFFull) ? 1 : 0;
}
__device__ __forceinline__ int load_node(const void* ei, int i64, long long idx) {
    return i64 ? (int)((const long long*)ei)[idx] : ((const int*)ei)[idx];
}

// ---------------- fp32 -> bf16 cast (streaming) ----------------
__global__ void cast_bf16_k(const float* __restrict__ in, ushort* __restrict__ outb,
                            long long n4) {
    long long i = (long long)blockIdx.x * 256 + threadIdx.x;
    if (i >= n4) return;
    ((uint2*)outb)[i] = packbf4(((const float4*)in)[i]);
}

// ---------------- weights -> bf16 col-major ----------------
__global__ void prep_wt_k(const float* __restrict__ W1, const float* __restrict__ W2,
                          ushort* __restrict__ W1t, ushort* __restrict__ W2t) {
    int i = blockIdx.x * 256 + threadIdx.x;
    if (i < 128 * 128) {
        int k = i >> 7, n = i & 127;
        W1t[n * 128 + k] = bf16rn(W1[k * 128 + n]);
    }
    if (i < 128 * 64) {
        int k = i >> 6, n = i & 63;
        W2t[n * 128 + k] = bf16rn(W2[k * 64 + n]);
    }
}

// ---------------- LDS-staged binning: edges -> per-bucket staging ----------------
__global__ __launch_bounds__(256) void binfill_k(const void* __restrict__ ei,
                                                 const int* __restrict__ flag,
                                                 int* __restrict__ cur,
                                                 unsigned* __restrict__ bstage) {
    __shared__ unsigned binned[EPB];      // 32 KB
    __shared__ int lcnt[NBPAD];
    __shared__ int lpos[NBPAD];
    __shared__ int gbase[NBPAD];
    __shared__ int tsum[256];
    int tid = threadIdx.x;
    long long e0 = (long long)blockIdx.x * EPB;
    int i64 = *flag;

    for (int i = tid; i < NBPAD; i += 256) lcnt[i] = 0;
    __syncthreads();

    // pass 1: histogram destination buckets
    for (int i = tid; i < EPB; i += 256) {
        long long e = e0 + i;
        if (e < NE) {
            int d = load_node(ei, i64, (long long)NE + e);
            atomicAdd(&lcnt[d >> 7], 1);
        }
    }
    __syncthreads();

    // exclusive scan over NBPAD counters, 4 consecutive per thread
    int base = tid * 4;
    int c0 = lcnt[base], c1 = lcnt[base + 1], c2 = lcnt[base + 2], c3 = lcnt[base + 3];
    int s = c0 + c1 + c2 + c3;
    tsum[tid] = s;
    __syncthreads();
    for (int off = 1; off < 256; off <<= 1) {
        int v = (tid >= off) ? tsum[tid - off] : 0;
        __syncthreads();
        tsum[tid] += v;
        __syncthreads();
    }
    int excl = tsum[tid] - s;
    int p0 = excl, p1 = excl + c0, p2 = p1 + c1, p3 = p2 + c2;
    lcnt[base] = p0; lcnt[base + 1] = p1; lcnt[base + 2] = p2; lcnt[base + 3] = p3;
    lpos[base] = p0; lpos[base + 1] = p1; lpos[base + 2] = p2; lpos[base + 3] = p3;
    if (base < NB)     gbase[base]     = c0 ? atomicAdd(&cur[base], c0) : 0;
    if (base + 1 < NB) gbase[base + 1] = c1 ? atomicAdd(&cur[base + 1], c1) : 0;
    if (base + 2 < NB) gbase[base + 2] = c2 ? atomicAdd(&cur[base + 2], c2) : 0;
    if (base + 3 < NB) gbase[base + 3] = c3 ? atomicAdd(&cur[base + 3], c3) : 0;
    __syncthreads();

    // pass 2: re-read (L2-hot) and scatter into binned LDS
    for (int i = tid; i < EPB; i += 256) {
        long long e = e0 + i;
        if (e < NE) {
            int sv = load_node(ei, i64, e);
            int d  = load_node(ei, i64, (long long)NE + e);
            int b  = d >> 7;
            int p  = atomicAdd(&lpos[b], 1);
            binned[p] = ((unsigned)(d & 127) << 17) | (unsigned)sv;
        }
    }
    __syncthreads();

    // flush contiguous runs into bucket regions
    for (int b = tid; b < NB; b += 256) {
        int start = lcnt[b], endp = lpos[b];
        int gb = gbase[b];
        unsigned* dst = bstage + (long long)b * CAPB;
        for (int k = start; k < endp; k++) {
            int go = gb + (k - start);
            if (go < CAPB) dst[go] = binned[k];
        }
    }
}

// ---------------- per-bucket LDS regroup -> dense CSR (uint2 {src,dst}) + deg ----------------
__global__ __launch_bounds__(256) void regroup_k(const int* __restrict__ cur,
                                                 const unsigned* __restrict__ bstage,
                                                 int* __restrict__ cnt,
                                                 int* __restrict__ rowstart,
                                                 uint2* __restrict__ g2,
                                                 float* __restrict__ dinv) {
    __shared__ unsigned stash[CAPB];
    __shared__ int lcnt[128], lofs[128], lpos[128], sc[128];
    int tid = threadIdx.x;
    int b = blockIdx.x;

    int total = cur[b];
    if (total > CAPB) total = CAPB;
    const unsigned* seg = bstage + (long long)b * CAPB;
    for (int i = tid; i < total; i += 256) stash[i] = seg[i];
    __syncthreads();

    if (tid < 128) { lcnt[tid] = 0; lpos[tid] = 0; }
    __syncthreads();
    for (int i = tid; i < total; i += 256)
        atomicAdd(&lcnt[stash[i] >> 17], 1);
    __syncthreads();

    if (tid < 128) sc[tid] = lcnt[tid];
    __syncthreads();
    for (int off = 1; off < 128; off <<= 1) {
        int v = 0;
        if (tid < 128 && tid >= off) v = sc[tid - off];
        __syncthreads();
        if (tid < 128) sc[tid] += v;
        __syncthreads();
    }
    if (tid < 128) {
        lofs[tid] = sc[tid] - lcnt[tid];
        int node = b * 128 + tid;
        if (node < NN) {
            cnt[node] = lcnt[tid];
            rowstart[node] = b * CAPB + lofs[tid];
            dinv[node] = rsqrtf((float)(lcnt[tid] + 1));   // +1: self-loop
        }
    }
    __syncthreads();

    uint2* g = g2 + (long long)b * CAPB;
    for (int i = tid; i < total; i += 256) {
        unsigned e = stash[i];
        int nl = e >> 17;
        int p = atomicAdd(&lpos[nl], 1);
        g[lofs[nl] + p] = make_uint2(e & 0x1FFFFu, (unsigned)(b * 128 + nl));
    }
}

// ---------------- per-edge norm precompute: {src,dst} -> {src, dinv[src]*dinv[dst]} ----------------
__global__ __launch_bounds__(256) void qn_k(const int* __restrict__ cur,
                                            const float* __restrict__ dinv,
                                            uint2* __restrict__ g2) {
    int b = blockIdx.x;
    int total = cur[b];
    if (total > CAPB) total = CAPB;
    uint2* g = g2 + (long long)b * CAPB;
    for (int i = threadIdx.x; i < total; i += 256) {
        uint2 e = g[i];
        float q = dinv[e.x] * dinv[e.y];
        g[i] = make_uint2(e.x, __float_as_uint(q));
    }
}

// ---------------- CSR pull v4: LDS-staged edges + forced 8-deep gather pipeline ----------------
// Edge entries staged to LDS once (coalesced, wave-internal, no barrier). Inner loop's only
// vmem class is the gathers; 8 statically-indexed in-flight gathers per wave, each consumed
// one full 8-slot rotation after issue.
template <int LPN, bool BIAS, bool OUTB>
__global__ __launch_bounds__(256) void pull4_k(const uint2* __restrict__ g2,
                                               const int* __restrict__ rowstart,
                                               const int* __restrict__ cnt,
                                               const float* __restrict__ dinv,
                                               const ushort* __restrict__ hb,
                                               const float* __restrict__ bias,
                                               void* __restrict__ out) {
    __shared__ uint2 ed[256 / LPN][MAXE];     // LPN=32: 4 KB, LPN=16: 8 KB
    int tid = threadIdx.x;
    int nib = tid / LPN;
    int lane = tid & (LPN - 1);
    int node = xcd_swz(blockIdx.x, (int)gridDim.x) * (256 / LPN) + nib;
    if (node >= NN) return;

    const uint2* h2 = (const uint2*)hb;
    float di = dinv[node];
    float w0 = di * di;
    float4 A = make_float4(0.f, 0.f, 0.f, 0.f);
    float4 B = make_float4(0.f, 0.f, 0.f, 0.f);
    {
        float4 hv = bf2x4(h2[(unsigned)node * LPN + lane]);
        A.x = hv.x * w0; A.y = hv.y * w0; A.z = hv.z * w0; A.w = hv.w * w0;
    }

    int deg = cnt[node];
    const uint2* row = g2 + rowstart[node];
    int s = deg < MAXE ? deg : MAXE;

    // stage this node's edges into LDS (contiguous 8B*LPN bursts, wave-internal)
    for (int t = lane; t < s; t += LPN) ed[nib][t] = row[t];

    int j = 0;
    if (s >= 8) {
        uint2 v[8];
        unsigned q[8];
#pragma unroll
        for (int t = 0; t < 8; t++) {
            uint2 e = ed[nib][t];
            q[t] = e.y;
            v[t] = h2[e.x * LPN + lane];
        }
        for (; j + 16 <= s; j += 8) {
#pragma unroll
            for (int t = 0; t < 8; t++) {
                uint2 e = ed[nib][j + 8 + t];          // LDS, cheap
                uint2 nv = h2[e.x * LPN + lane];       // issue gather (consumed next rotation)
                if (t & 1) acc4(B, v[t], q[t]);        // consume gather issued 8 slots ago
                else       acc4(A, v[t], q[t]);
                v[t] = nv; q[t] = e.y;
            }
        }
#pragma unroll
        for (int t = 0; t < 8; t++) {
            if (t & 1) acc4(B, v[t], q[t]);
            else       acc4(A, v[t], q[t]);
        }
        j += 8;
    }
    for (; j < s; j++) {                               // staged remainder (<8 left)
        uint2 e = ed[nib][j];
        uint2 v0 = h2[e.x * LPN + lane];
        acc4(A, v0, e.y);
    }
    for (; j < deg; j++) {                             // overflow beyond MAXE (rare)
        uint2 e = row[j];
        uint2 v0 = h2[e.x * LPN + lane];
        acc4(A, v0, e.y);
    }

    float4 o;
    o.x = A.x + B.x; o.y = A.y + B.y; o.z = A.z + B.z; o.w = A.w + B.w;
    if (BIAS) {
        float4 bb = ((const float4*)bias)[lane];
        o.x += bb.x; o.y += bb.y; o.z += bb.z; o.w += bb.w;
    }
    if (OUTB)
        ((uint2*)out)[(unsigned)node * LPN + lane] = packbf4(o);
    else
        ((float4*)out)[(unsigned)node * LPN + lane] = o;
}

// ---------------- MFMA fused double GEMM ----------------
__global__ __launch_bounds__(256) void dgemm_mfma_k(const ushort* __restrict__ Ab,
                                                    const ushort* __restrict__ W1t,
                                                    const float* __restrict__ b1,
                                                    const ushort* __restrict__ W2t,
                                                    ushort* __restrict__ H2b) {
    __shared__ ushort Tt[4][32 * DPAD];
    __shared__ ushort Ot[4][32 * OPAD];
    int tid = threadIdx.x;
    int wv = tid >> 6, lane = tid & 63;
    int m16 = lane & 15, quad = lane >> 4;
    int row0 = blockIdx.x * 128 + wv * 32;

    short8 af[2][4];
#pragma unroll
    for (int mt = 0; mt < 2; mt++)
#pragma unroll
        for (int kc = 0; kc < 4; kc++)
            af[mt][kc] = *(const short8*)(Ab + (long long)(row0 + mt * 16 + m16) * 128
                                          + kc * 32 + quad * 8);
    f32x4 accA[2][8];
#pragma unroll
    for (int mt = 0; mt < 2; mt++)
#pragma unroll
        for (int nt = 0; nt < 8; nt++) accA[mt][nt] = (f32x4){0.f, 0.f, 0.f, 0.f};

#pragma unroll
    for (int nt = 0; nt < 8; nt++) {
#pragma unroll
        for (int kc = 0; kc < 4; kc++) {
            short8 bf = *(const short8*)(W1t + (nt * 16 + m16) * 128 + kc * 32 + quad * 8);
            accA[0][nt] = __builtin_amdgcn_mfma_f32_16x16x32_bf16(af[0][kc], bf, accA[0][nt], 0, 0, 0);
            accA[1][nt] = __builtin_amdgcn_mfma_f32_16x16x32_bf16(af[1][kc], bf, accA[1][nt], 0, 0, 0);
        }
    }

#pragma unroll
    for (int nt = 0; nt < 8; nt++) {
        float bb = b1[nt * 16 + m16];
#pragma unroll
        for (int mt = 0; mt < 2; mt++)
#pragma unroll
            for (int r = 0; r < 4; r++) {
                float v = fmaxf(accA[mt][nt][r] + bb, 0.f);
                Tt[wv][(mt * 16 + quad * 4 + r) * DPAD + nt * 16 + m16] = bf16rn(v);
            }
    }
    __syncthreads();

    f32x4 accB[2][4];
#pragma unroll
    for (int mt = 0; mt < 2; mt++)
#pragma unroll
        for (int nt = 0; nt < 4; nt++) accB[mt][nt] = (f32x4){0.f, 0.f, 0.f, 0.f};

#pragma unroll
    for (int nt = 0; nt < 4; nt++) {
#pragma unroll
        for (int kc = 0; kc < 4; kc++) {
            short8 bf = *(const short8*)(W2t + (nt * 16 + m16) * 128 + kc * 32 + quad * 8);
#pragma unroll
            for (int mt = 0; mt < 2; mt++) {
                short8 aT = *(const short8*)(&Tt[wv][(mt * 16 + m16) * DPAD + kc * 32 + quad * 8]);
                accB[mt][nt] = __builtin_amdgcn_mfma_f32_16x16x32_bf16(aT, bf, accB[mt][nt], 0, 0, 0);
            }
        }
    }

#pragma unroll
    for (int nt = 0; nt < 4; nt++)
#pragma unroll
        for (int mt = 0; mt < 2; mt++)
#pragma unroll
            for (int r = 0; r < 4; r++)
                Ot[wv][(mt * 16 + quad * 4 + r) * OPAD + nt * 16 + m16] = bf16rn(accB[mt][nt][r]);
    __syncthreads();

    uint4* H4 = (uint4*)H2b;
#pragma unroll
    for (int it = 0; it < 4; it++) {
        int idx = it * 64 + lane;
        int r = idx >> 3, c = idx & 7;
        int grow = row0 + r;
        if (grow < NN) {
            uint4 v = *(const uint4*)(&Ot[wv][r * OPAD + c * 8]);
            H4[(long long)grow * 8 + c] = v;
        }
    }
}

// ---------------- launch ----------------
extern "C" void kernel_launch(void* const* d_in, const int* in_sizes, int n_in,
                              void* d_out, int out_size, void* d_ws, size_t ws_size,
                              hipStream_t stream) {
    const float* x  = (const float*)d_in[0];
    const void*  ei = d_in[1];
    const float* W1 = (const float*)d_in[2];
    const float* b1 = (const float*)d_in[3];
    const float* W2 = (const float*)d_in[4];
    const float* b2 = (const float*)d_in[5];
    float* out = (float*)d_out;
    char* ws = (char*)d_ws;

    // Layout (~98 MB of the >=125 MB proven ws):
    int*      flag     = (int*)ws;
    int*      cur      = (int*)(ws + 0x1000);        // 3.1 KB
    int*      cnt      = (int*)(ws + 0x10000);       // 400 KB
    int*      rowstart = (int*)(ws + 0x80000);       // 400 KB
    unsigned* bstage   = (unsigned*)(ws + 0x100000); // 782*3072*4 = 9.6 MB
    uint2*    g2       = (uint2*)(ws + 0xB00000);    // 782*3072*8 = 19.2 MB
    ushort*   xb       = (ushort*)(ws + 0x1E00000);  // 25.6 MB
    ushort*   aggxb    = (ushort*)(ws + 0x3700000);  // 25.6 MB (+pad rows)
    ushort*   h2b      = (ushort*)(ws + 0x5000000);  // 12.8 MB
    ushort*   W1t      = (ushort*)(ws + 0x5D00000);  // 32 KB
    ushort*   W2t      = (ushort*)(ws + 0x5D10000);  // 16 KB
    float*    dinv     = (float*)(ws + 0x5D20000);   // 400 KB

    hipMemsetAsync(cur, 0, NB * sizeof(int), stream);
    detect_i64_k<<<1, 64, 0, stream>>>((const unsigned*)ei, flag);
    cast_bf16_k<<<(NN * 32 + 255) / 256, 256, 0, stream>>>(x, xb, (long long)NN * 32);
    prep_wt_k<<<64, 256, 0, stream>>>(W1, W2, W1t, W2t);
    binfill_k<<<(NE + EPB - 1) / EPB, 256, 0, stream>>>(ei, flag, cur, bstage);
    regroup_k<<<NB, 256, 0, stream>>>(cur, bstage, cnt, rowstart, g2, dinv);
    qn_k<<<NB, 256, 0, stream>>>(cur, dinv, g2);

    // layer 1 aggregate-first: aggxb = bf16( A_norm @ x ), LPN=32 (8 nodes/block)
    pull4_k<32, false, true><<<(NN + 7) / 8, 256, 0, stream>>>(g2, rowstart, cnt, dinv,
                                                               xb, nullptr, aggxb);
    // fused transforms on MFMA: h2b = bf16( relu(aggxb@W1 + b1) @ W2 )
    dgemm_mfma_k<<<NROWPAD / 128, 256, 0, stream>>>(aggxb, W1t, b1, W2t, h2b);

    // layer 2 aggregate: out = A_norm @ h2 + b2 (fp32 out), LPN=16 (16 nodes/block)
    pull4_k<16, true, false><<<(NN + 15) / 16, 256, 0, stream>>>(g2, rowstart, cnt, dinv,
                                                                 h2b, b2, out);
}